// Round 20
// baseline (115.593 us; speedup 1.0000x reference)
//
#include <hip/hip_runtime.h>
#include <math.h>

#define NN   1000
#define DD   128
#define CTXN 130
#define NEG_BIG (-1.0e30f)

// fast tanh via __expf; exact +-1 at saturation, no NaN (clamp keeps exp finite)
__device__ __forceinline__ float fast_tanh(float a) {
    a = fminf(fmaxf(a, -20.f), 20.f);
    const float ex = __expf(-2.0f * a);
    return (1.0f - ex) / (1.0f + ex);
}

// ============================================================================
// 3-dispatch pipeline (R19 + fast-shape k1, serial work pushed to consumers):
//  k1p (B*8x256): mean partials ONLY (proven ~6-7 TB/s shape)
//  kB  (B*8x512): per-block prologue {merge mean partials -> query -> qproj ->
//                 in-LDS slice compaction} then R19 slim streaming + headsp fold
//  k4  (B x1024): per-block {probe+full compaction} -> dinv -> heads -> glimpse
//                 -> g2 -> logits (branchless) -> max-free log_softmax
// ws: meanp[B][1024] | headsp[B][8][128] | stats[B][64]
// Shared softmax shift C=0 (|compat| << 80; fminf guard) -> plain-sum merge.
// Lessons: dispatch boundary ~2-3us (R16); (512,4) caps VGPR=64 (R11);
// blockIdx%8 = XCD -> balance slices (R13); heads linear in wembp_s (R18).
// ============================================================================

// ---------------- K1p: per-(b,s) partial column sums ----------------
__global__ __launch_bounds__(256, 8)
void k1p_meanpart(const float* __restrict__ emb, float* __restrict__ meanp) {
    const int b = blockIdx.x >> 3, s = blockIdx.x & 7;
    const int t = threadIdx.x;
    const float* eb = emb + (size_t)b * (NN * DD);
    __shared__ __align__(16) float s_red[8 * 128];
    const int c4 = t & 31, rg = t >> 5;
    float4 a = make_float4(0.f, 0.f, 0.f, 0.f);
    for (int nl = rg; nl < 125; nl += 8) {
        const float4 v = *(const float4*)(eb + (size_t)(s * 125 + nl) * DD + c4 * 4);
        a.x += v.x; a.y += v.y; a.z += v.z; a.w += v.w;
    }
    ((float4*)s_red)[rg * 32 + c4] = a;
    __syncthreads();
    if (t < 128) {
        float v = 0.f;
        #pragma unroll
        for (int g = 0; g < 8; ++g) v += s_red[g * 128 + t];
        meanp[(size_t)b * 1024 + s * 128 + t] = v;
    }
}

// ---------------- KB: prologue (qproj + slice compaction) + slim streaming ----------------
// lane = (rg, cl): rg in [0,4) = head PAIR (heads 2rg, 2rg+1); cl = col octet.
// Wave w does compact position it*8 + w. <=64 VGPR; 4 blk/CU (LDS ~38.9 KB).
__global__ __launch_bounds__(512, 4)
void kB_stream(const float* __restrict__ emb, const float* __restrict__ meanp,
               const float* __restrict__ stepc, const void* __restrict__ maskp,
               const float* __restrict__ Wn, const float* __restrict__ Wf,
               const float* __restrict__ Ws,
               float* __restrict__ headsp, float* __restrict__ stats) {
    const int b = blockIdx.x >> 3, s = blockIdx.x & 7;
    const int t = threadIdx.x, w = t >> 6, lane = t & 63;
    const int rg = lane >> 4, cl = lane & 15;
    const float* eb = emb + (size_t)b * (NN * DD);
    __shared__ __align__(16) float s_qpT[1024];         // 4 KB
    __shared__ __align__(16) float s_part[8 * 8 * 132]; // 33.8 KB; multi-use
    __shared__ float s_sumw[64];
    __shared__ int s_idx[128];
    __shared__ unsigned long long s_bal[16];
    __shared__ int s_woff[16];
    __shared__ int s_cnt, s_misint;
    // prologue aliases into s_part (dead before the accumulator epilogue)
    float* s_mean = s_part;          // 128
    float* s_q    = s_part + 128;    // 128
    float* s_scr  = s_part + 256;    // 512
    // ---- mask probe (int32 layout: bytes 1 mod 4 all zero) ----
    if (t == 0) {
        const unsigned char* mb8 = (const unsigned char*)maskp;
        int any = 0;
        for (int k = 0; k < 64; ++k) any |= mb8[4 * k + 1];
        s_misint = (any == 0) ? 1 : 0;
    }
    // ---- mean merge ----
    if (t < 128) {
        float v = 0.f;
        #pragma unroll
        for (int g = 0; g < 8; ++g) v += meanp[(size_t)b * 1024 + g * 128 + t];
        s_mean[t] = v * (1.0f / (float)NN);
    }
    __syncthreads();
    // ---- query[d] = mean.Wf[:,d] + sc.Ws[:,d], 4-way split ----
    {
        const int d = t & 127, p = t >> 7;
        float a = 0.f;
        for (int i = 32 * p; i < 32 * p + 32; ++i)
            a = fmaf(s_mean[i], Wf[i * DD + d], a);
        const float* scb = stepc + (size_t)b * CTXN;
        const int c0 = 32 * p, c1 = (p == 3) ? CTXN : 32 * p + 32;
        for (int c = c0; c < c1; ++c)
            a = fmaf(scb[c], Ws[c * DD + d], a);
        s_scr[p * 128 + d] = a;
    }
    __syncthreads();
    if (t < 128) s_q[t] = s_scr[t] + s_scr[128 + t] + s_scr[256 + t] + s_scr[384 + t];
    __syncthreads();
    // ---- qproj[h][i] = 0.25 * sum_j Wn[i,16h+j] q[16h+j] ----
    {
        const int i = t & 127, p = t >> 7;
        #pragma unroll
        for (int u = 0; u < 2; ++u) {
            const int h = p + 4 * u;
            float a = 0.f;
            #pragma unroll
            for (int j = 0; j < 16; ++j)
                a = fmaf(Wn[i * 384 + h * 16 + j], s_q[h * 16 + j], a);
            s_qpT[h * 128 + i] = a * 0.25f;
        }
    }
    // ---- compaction (2 rounds of 512), slice window only ----
    {
        const unsigned char* mk8 = (const unsigned char*)maskp + (size_t)b * NN;
        const int* mk32 = (const int*)maskp + (size_t)b * NN;
        const int misint = s_misint;
        #pragma unroll
        for (int r = 0; r < 2; ++r) {
            const int gi = r * 512 + t;
            int um = 0;
            if (gi < NN) um = misint ? (mk32[gi] == 0) : (mk8[gi] == 0);
            const unsigned long long bal = __ballot(um);
            if (lane == 0) s_bal[r * 8 + w] = bal;
        }
        __syncthreads();
        if (t == 0) {
            int o = 0;
            #pragma unroll
            for (int k = 0; k < 16; ++k) { s_woff[k] = o; o += (int)__popcll(s_bal[k]); }
            s_cnt = o;
        }
        __syncthreads();
        const int cnt = s_cnt;
        const int lo = (s * cnt) >> 3, hi = ((s + 1) * cnt) >> 3;
        #pragma unroll
        for (int r = 0; r < 2; ++r) {
            const int gi = r * 512 + t;
            const unsigned long long bal = s_bal[r * 8 + w];
            if ((bal >> lane) & 1ULL) {
                const int pos = s_woff[r * 8 + w] +
                    (int)__popcll(bal & ((lane == 0) ? 0ULL : (~0ULL >> (64 - lane))));
                if (pos >= lo && pos < hi) s_idx[pos - lo] = gi;
            }
        }
    }
    __syncthreads();
    const int cnt = s_cnt;
    const int lo = (s * cnt) >> 3, hi = ((s + 1) * cnt) >> 3;
    const int nrows = hi - lo;              // <= 125
    // ---- main streaming (R19, byte-identical) ----
    const int h0 = 2 * rg, h1 = 2 * rg + 1;
    const float4 qa0 = *(const float4*)&s_qpT[h0 * 128 + cl * 8];
    const float4 qa1 = *(const float4*)&s_qpT[h0 * 128 + cl * 8 + 4];
    const float4 qb0 = *(const float4*)&s_qpT[h1 * 128 + cl * 8];
    const float4 qb1 = *(const float4*)&s_qpT[h1 * 128 + cl * 8 + 4];
    float4 a0A = make_float4(0.f,0.f,0.f,0.f), a0B = a0A;
    float4 a1A = a0A, a1B = a0A;
    float ps0 = 0.f, ps1 = 0.f;
    const int mainIt = nrows >> 3;
    for (int it = 0; it < mainIt; ++it) {
        const int rp = it * 8 + w;
        const int n = s_idx[rp];
        const float4 e0 = *(const float4*)(eb + (size_t)n * DD + cl * 8);
        const float4 e1 = *(const float4*)(eb + (size_t)n * DD + cl * 8 + 4);
        float c0 = e0.x * qa0.x;
        c0 = fmaf(e0.y, qa0.y, c0); c0 = fmaf(e0.z, qa0.z, c0); c0 = fmaf(e0.w, qa0.w, c0);
        c0 = fmaf(e1.x, qa1.x, c0); c0 = fmaf(e1.y, qa1.y, c0);
        c0 = fmaf(e1.z, qa1.z, c0); c0 = fmaf(e1.w, qa1.w, c0);
        float c1 = e0.x * qb0.x;
        c1 = fmaf(e0.y, qb0.y, c1); c1 = fmaf(e0.z, qb0.z, c1); c1 = fmaf(e0.w, qb0.w, c1);
        c1 = fmaf(e1.x, qb1.x, c1); c1 = fmaf(e1.y, qb1.y, c1);
        c1 = fmaf(e1.z, qb1.z, c1); c1 = fmaf(e1.w, qb1.w, c1);
        c0 += __shfl_xor(c0, 1, 16); c1 += __shfl_xor(c1, 1, 16);
        c0 += __shfl_xor(c0, 2, 16); c1 += __shfl_xor(c1, 2, 16);
        c0 += __shfl_xor(c0, 4, 16); c1 += __shfl_xor(c1, 4, 16);
        c0 += __shfl_xor(c0, 8, 16); c1 += __shfl_xor(c1, 8, 16);
        const float p0 = __expf(fminf(c0, 80.f));
        const float p1 = __expf(fminf(c1, 80.f));
        ps0 += p0; ps1 += p1;
        a0A.x = fmaf(p0, e0.x, a0A.x); a0A.y = fmaf(p0, e0.y, a0A.y);
        a0A.z = fmaf(p0, e0.z, a0A.z); a0A.w = fmaf(p0, e0.w, a0A.w);
        a0B.x = fmaf(p0, e1.x, a0B.x); a0B.y = fmaf(p0, e1.y, a0B.y);
        a0B.z = fmaf(p0, e1.z, a0B.z); a0B.w = fmaf(p0, e1.w, a0B.w);
        a1A.x = fmaf(p1, e0.x, a1A.x); a1A.y = fmaf(p1, e0.y, a1A.y);
        a1A.z = fmaf(p1, e0.z, a1A.z); a1A.w = fmaf(p1, e0.w, a1A.w);
        a1B.x = fmaf(p1, e1.x, a1B.x); a1B.y = fmaf(p1, e1.y, a1B.y);
        a1B.z = fmaf(p1, e1.z, a1B.z); a1B.w = fmaf(p1, e1.w, a1B.w);
    }
    if (mainIt * 8 < nrows) {   // guarded tail
        const int rp = mainIt * 8 + w;
        const bool valid = (rp < nrows);
        const int n = s_idx[rp & 127];
        float4 e0 = make_float4(0.f,0.f,0.f,0.f), e1 = e0;
        if (valid) {
            e0 = *(const float4*)(eb + (size_t)n * DD + cl * 8);
            e1 = *(const float4*)(eb + (size_t)n * DD + cl * 8 + 4);
        }
        float c0 = e0.x * qa0.x;
        c0 = fmaf(e0.y, qa0.y, c0); c0 = fmaf(e0.z, qa0.z, c0); c0 = fmaf(e0.w, qa0.w, c0);
        c0 = fmaf(e1.x, qa1.x, c0); c0 = fmaf(e1.y, qa1.y, c0);
        c0 = fmaf(e1.z, qa1.z, c0); c0 = fmaf(e1.w, qa1.w, c0);
        float c1 = e0.x * qb0.x;
        c1 = fmaf(e0.y, qb0.y, c1); c1 = fmaf(e0.z, qb0.z, c1); c1 = fmaf(e0.w, qb0.w, c1);
        c1 = fmaf(e1.x, qb1.x, c1); c1 = fmaf(e1.y, qb1.y, c1);
        c1 = fmaf(e1.z, qb1.z, c1); c1 = fmaf(e1.w, qb1.w, c1);
        c0 += __shfl_xor(c0, 1, 16); c1 += __shfl_xor(c1, 1, 16);
        c0 += __shfl_xor(c0, 2, 16); c1 += __shfl_xor(c1, 2, 16);
        c0 += __shfl_xor(c0, 4, 16); c1 += __shfl_xor(c1, 4, 16);
        c0 += __shfl_xor(c0, 8, 16); c1 += __shfl_xor(c1, 8, 16);
        const float p0 = valid ? __expf(fminf(c0, 80.f)) : 0.f;
        const float p1 = valid ? __expf(fminf(c1, 80.f)) : 0.f;
        ps0 += p0; ps1 += p1;
        a0A.x = fmaf(p0, e0.x, a0A.x); a0A.y = fmaf(p0, e0.y, a0A.y);
        a0A.z = fmaf(p0, e0.z, a0A.z); a0A.w = fmaf(p0, e0.w, a0A.w);
        a0B.x = fmaf(p0, e1.x, a0B.x); a0B.y = fmaf(p0, e1.y, a0B.y);
        a0B.z = fmaf(p0, e1.z, a0B.z); a0B.w = fmaf(p0, e1.w, a0B.w);
        a1A.x = fmaf(p1, e0.x, a1A.x); a1A.y = fmaf(p1, e0.y, a1A.y);
        a1A.z = fmaf(p1, e0.z, a1A.z); a1A.w = fmaf(p1, e0.w, a1A.w);
        a1B.x = fmaf(p1, e1.x, a1B.x); a1B.y = fmaf(p1, e1.y, a1B.y);
        a1B.z = fmaf(p1, e1.z, a1B.z); a1B.w = fmaf(p1, e1.w, a1B.w);
    }
    __syncthreads();   // prologue aliases of s_part are dead; safe to overwrite
    *(float4*)&s_part[(w * 8 + h0) * 132 + cl * 8]     = a0A;
    *(float4*)&s_part[(w * 8 + h0) * 132 + cl * 8 + 4] = a0B;
    *(float4*)&s_part[(w * 8 + h1) * 132 + cl * 8]     = a1A;
    *(float4*)&s_part[(w * 8 + h1) * 132 + cl * 8 + 4] = a1B;
    if (cl == 0) { s_sumw[w * 8 + h0] = ps0; s_sumw[w * 8 + h1] = ps1; }
    __syncthreads();
    // ---- reduce wave partials, stash wemb_s into s_part[0..1024) ----
    float vres0, vres1;
    {
        const int i0 = t, i1 = t + 512;
        const int hA = i0 >> 7, cA = i0 & 127;
        const int hB = i1 >> 7, cB = i1 & 127;
        float v0 = 0.f, v1 = 0.f;
        #pragma unroll
        for (int w2 = 0; w2 < 8; ++w2) {
            v0 += s_part[(w2 * 8 + hA) * 132 + cA];
            v1 += s_part[(w2 * 8 + hB) * 132 + cB];
        }
        vres0 = v0; vres1 = v1;
    }
    __syncthreads();
    s_part[t]       = vres0;
    s_part[t + 512] = vres1;
    __syncthreads();
    // ---- headsp_s[j] = sum_i Wv[i,j] * wemb_s[j>>4][i], 4-way i-split ----
    {
        const int j = t & 127, p = t >> 7;
        const int h = j >> 4;
        float a = 0.f;
        for (int i = 32 * p; i < 32 * p + 32; ++i)
            a = fmaf(Wn[i * 384 + 128 + j], s_part[h * 128 + i], a);
        s_part[1024 + p * 128 + j] = a;
    }
    __syncthreads();
    if (t < 128)
        headsp[(size_t)b * 1024 + s * 128 + t] =
            s_part[1024 + t] + s_part[1024 + 128 + t] +
            s_part[1024 + 256 + t] + s_part[1024 + 384 + t];
    if (t < 8) {
        float v = 0.f;
        #pragma unroll
        for (int w2 = 0; w2 < 8; ++w2) v += s_sumw[w2 * 8 + t];
        stats[(size_t)b * 64 + s * 8 + t] = v;
    }
}

// ---------------- K4': local compaction -> heads -> glimpse -> g2 -> logits -> log_softmax ----------------
__global__ __launch_bounds__(1024, 4)
void k4_fused(const float* __restrict__ emb, const float* __restrict__ headsp,
              const float* __restrict__ stats, const void* __restrict__ maskp,
              const float* __restrict__ Wn, const float* __restrict__ Wo,
              float* __restrict__ out) {
    const int b = blockIdx.x, t = threadIdx.x;
    const int w = t >> 6, lane = t & 63;
    const int rg = lane >> 4, cl = lane & 15;
    const float* eb = emb + (size_t)b * (NN * DD);
    __shared__ float s_dinv[8];
    __shared__ __align__(16) float s_red[1024];
    __shared__ float s_h[128], s_gl[128], s_g2[128];
    __shared__ float s_logits[1000];
    __shared__ int s_idxf[1024];
    __shared__ float s_r2[32];
    __shared__ float s_lse;
    __shared__ unsigned long long s_bal[16];
    __shared__ int s_woff[16];
    __shared__ int s_cnt, s_misint;
    if (t < NN) s_logits[t] = NEG_BIG;
    if (t == 0) {   // mask layout probe
        const unsigned char* mb8 = (const unsigned char*)maskp;
        int any = 0;
        for (int k = 0; k < 64; ++k) any |= mb8[4 * k + 1];
        s_misint = (any == 0) ? 1 : 0;
    }
    if (t < 8) {
        float den = 0.f;
        #pragma unroll
        for (int ss = 0; ss < 8; ++ss) den += stats[(size_t)b * 64 + ss * 8 + t];
        s_dinv[t] = 1.0f / den;
    }
    __syncthreads();
    // ---- local compaction (1 round, 1024 threads) ----
    {
        const unsigned char* mk8 = (const unsigned char*)maskp + (size_t)b * NN;
        const int* mk32 = (const int*)maskp + (size_t)b * NN;
        int um = 0;
        if (t < NN) um = s_misint ? (mk32[t] == 0) : (mk8[t] == 0);
        const unsigned long long bal = __ballot(um);
        if (lane == 0) s_bal[w] = bal;
        __syncthreads();
        if (t == 0) {
            int o = 0;
            #pragma unroll
            for (int k = 0; k < 16; ++k) { s_woff[k] = o; o += (int)__popcll(s_bal[k]); }
            s_cnt = o;
        }
        __syncthreads();
        if (um) {
            const int pos = s_woff[w] +
                (int)__popcll(bal & ((lane == 0) ? 0ULL : (~0ULL >> (64 - lane))));
            s_idxf[pos] = t;
        }
    }
    // ---- heads[j] = dinv[j>>4] * sum_s headsp_s[j] ----
    if (t < 128) {
        float v = 0.f;
        #pragma unroll
        for (int ss = 0; ss < 8; ++ss) v += headsp[(size_t)b * 1024 + ss * 128 + t];
        s_h[t] = v * s_dinv[t >> 4];
    }
    __syncthreads();
    {   // glimpse[d] = sum_j heads[j] Wo[j,d], 8-way j-split
        const int d = t & 127, p = t >> 7;
        float a = 0.f;
        for (int j = 16 * p; j < 16 * p + 16; ++j)
            a = fmaf(s_h[j], Wo[j * DD + d], a);
        s_red[p * 128 + d] = a;
    }
    __syncthreads();
    if (t < 128) {
        float v = 0.f;
        #pragma unroll
        for (int p = 0; p < 8; ++p) v += s_red[p * 128 + t];
        s_gl[t] = v;
    }
    __syncthreads();
    {   // g2[i] = (1/sqrt(128)) sum_d Wl[i,d] glimpse[d]
        const int i = t & 127, p = t >> 7;
        float a = 0.f;
        for (int d = 16 * p; d < 16 * p + 16; ++d)
            a = fmaf(Wn[i * 384 + 256 + d], s_gl[d], a);
        s_red[p * 128 + i] = a;
    }
    __syncthreads();
    if (t < 128) {
        float v = 0.f;
        #pragma unroll
        for (int p = 0; p < 8; ++p) v += s_red[p * 128 + t];
        s_g2[t] = v * 0.08838834764831845f;
    }
    __syncthreads();
    // ---- logits over compacted rows: branchless main + guarded tail ----
    {
        const int cnt = s_cnt;
        const float4 ga = *(const float4*)&s_g2[cl * 8];
        const float4 gb = *(const float4*)&s_g2[cl * 8 + 4];
        const int mainL = cnt >> 6;
        for (int it = 0; it < mainL; ++it) {
            const int pos = it * 64 + w * 4 + rg;
            const int n = s_idxf[pos];
            const float4 e0 = *(const float4*)(eb + (size_t)n * DD + cl * 8);
            const float4 e1 = *(const float4*)(eb + (size_t)n * DD + cl * 8 + 4);
            float a = e0.x * ga.x;
            a = fmaf(e0.y, ga.y, a);
            a = fmaf(e0.z, ga.z, a);
            a = fmaf(e0.w, ga.w, a);
            a = fmaf(e1.x, gb.x, a);
            a = fmaf(e1.y, gb.y, a);
            a = fmaf(e1.z, gb.z, a);
            a = fmaf(e1.w, gb.w, a);
            a += __shfl_xor(a, 1, 16);
            a += __shfl_xor(a, 2, 16);
            a += __shfl_xor(a, 4, 16);
            a += __shfl_xor(a, 8, 16);
            if (cl == 0)
                s_logits[n] = 10.0f * fast_tanh(a);
        }
        if (mainL * 64 < cnt) {
            const int pos = mainL * 64 + w * 4 + rg;
            const bool valid = (pos < cnt);
            const int n = s_idxf[pos & 1023];
            float a = 0.f;
            if (valid) {
                const float4 e0 = *(const float4*)(eb + (size_t)n * DD + cl * 8);
                const float4 e1 = *(const float4*)(eb + (size_t)n * DD + cl * 8 + 4);
                a = e0.x * ga.x;
                a = fmaf(e0.y, ga.y, a);
                a = fmaf(e0.z, ga.z, a);
                a = fmaf(e0.w, ga.w, a);
                a = fmaf(e1.x, gb.x, a);
                a = fmaf(e1.y, gb.y, a);
                a = fmaf(e1.z, gb.z, a);
                a = fmaf(e1.w, gb.w, a);
            }
            a += __shfl_xor(a, 1, 16);
            a += __shfl_xor(a, 2, 16);
            a += __shfl_xor(a, 4, 16);
            a += __shfl_xor(a, 8, 16);
            if (cl == 0 && valid)
                s_logits[n] = 10.0f * fast_tanh(a);
        }
    }
    __syncthreads();
    // ---- max-free log_softmax (|logits|<=10; __expf(NEG_BIG)=0) ----
    {
        float sum = (t < NN) ? __expf(s_logits[t]) : 0.f;
        #pragma unroll
        for (int o = 32; o; o >>= 1) sum += __shfl_xor(sum, o, 64);
        if (lane == 0) s_r2[w] = sum;
        __syncthreads();
        if (t == 0) {
            float ss = 0.f;
            #pragma unroll
            for (int i = 0; i < 16; ++i) ss += s_r2[i];
            s_lse = logf(ss);
        }
        __syncthreads();
        if (t < NN) out[(size_t)b * NN + t] = s_logits[t] - s_lse;
    }
}

extern "C" void kernel_launch(void* const* d_in, const int* in_sizes, int n_in,
                              void* d_out, int out_size, void* d_ws, size_t ws_size,
                              hipStream_t stream) {
    const float* emb   = (const float*)d_in[0];
    const float* stepc = (const float*)d_in[1];
    const void*  mask  = (const void*)d_in[2];
    const float* Wn = (const float*)d_in[3];
    const float* Wf = (const float*)d_in[4];
    const float* Ws = (const float*)d_in[5];
    const float* Wo = (const float*)d_in[6];
    float* out = (float*)d_out;
    const int B = in_sizes[0] / (NN * DD);  // 256

    float* wsf = (float*)d_ws;
    const size_t n_meanp = (size_t)B * 1024;
    const size_t n_hp    = (size_t)B * 1024;

    float* meanp  = wsf;
    float* headsp = meanp + n_meanp;
    float* stats  = headsp + n_hp;

    k1p_meanpart<<<B * 8, 256, 0, stream>>>(emb, meanp);
    kB_stream   <<<B * 8, 512, 0, stream>>>(emb, meanp, stepc, mask, Wn, Wf, Ws,
                                            headsp, stats);
    k4_fused    <<<B,     1024, 0, stream>>>(emb, headsp, stats, mask, Wn, Wo, out);
}

// Round 21
// 78.280 us; speedup vs baseline: 1.4767x; 1.4767x over previous
//
#include <hip/hip_runtime.h>
#include <math.h>

#define NN   1000
#define DD   128
#define CTXN 130
#define NEG_BIG (-1.0e30f)

// fast tanh via __expf; exact +-1 at saturation, no NaN (clamp keeps exp finite)
__device__ __forceinline__ float fast_tanh(float a) {
    a = fminf(fmaxf(a, -20.f), 20.f);
    const float ex = __expf(-2.0f * a);
    return (1.0f - ex) / (1.0f + ex);
}

// ============================================================================
// 3-dispatch pipeline (R19 champion, restored verbatim after R20 regression):
//  k1_fused (B x1024): emb -> mean -> query -> qproj[h][i] + row compaction
//  kB       (B*8x512): slim streaming over balanced compacted rows (2 heads x
//                      8 cols per lane, <=64 VGPR, 4 blk/CU, XCD-balanced)
//                      + headsp fold epilogue (slice partials through Wv).
//  k4_fused (B x1024): dinv -> heads -> glimpse -> g2 -> logits (dynamic trip,
//                      branchless main) -> max-free log_softmax
// ws: qpt[B][1024] | headsp[B][8][128] | stats[B][64] | idx[B][1024] | cnt[B]
// Shared softmax shift C=0 (|compat| << 80; fminf guard) -> plain-sum merge.
// Lessons: dispatch boundary ~2-3us (R16); (512,4) caps VGPR=64 (R11);
// blockIdx%8 = XCD -> balance slices (R13); heads linear in wembp_s (R18);
// do NOT move qproj production into kB -- codegen demotes qa/qb to LDS
// re-reads (R20: VGPR 60->36, kB 26->82us). kB must stay byte-stable.
// ============================================================================

// ---------------- K1': mean + query + qproj + mask compaction ----------------
__global__ __launch_bounds__(1024, 4)
void k1_fused(const float* __restrict__ emb, const float* __restrict__ stepc,
              const void* __restrict__ maskp,
              const float* __restrict__ Wn, const float* __restrict__ Wf,
              const float* __restrict__ Ws,
              float* __restrict__ qpt, int* __restrict__ idxv, int* __restrict__ cntv) {
    const int b = blockIdx.x, t = threadIdx.x;
    const int w = t >> 6, lane = t & 63;
    const float* eb = emb + (size_t)b * (NN * DD);
    __shared__ __align__(16) float S[4096];
    __shared__ float s_mean[128], s_q[128];
    __shared__ int s_misint;
    __shared__ unsigned long long s_bal[16];
    __shared__ int s_woff[16];
    if (t == 0) {   // mask layout probe (int32: bytes 1 mod 4 all 0)
        const unsigned char* mb8 = (const unsigned char*)maskp;
        int any = 0;
        for (int k = 0; k < 64; ++k) any |= mb8[4 * k + 1];
        s_misint = (any == 0) ? 1 : 0;
    }
    {   // mean: 32 row-groups x 32 float4-columns
        const int c4 = t & 31, g = t >> 5;
        float4 a = make_float4(0.f, 0.f, 0.f, 0.f);
        for (int r = g; r < NN; r += 32) {
            const float4 v = *(const float4*)(eb + (size_t)r * DD + c4 * 4);
            a.x += v.x; a.y += v.y; a.z += v.z; a.w += v.w;
        }
        ((float4*)S)[g * 32 + c4] = a;
    }
    __syncthreads();
    if (t < 128) {
        float v = 0.f;
        #pragma unroll
        for (int g = 0; g < 32; ++g) v += S[g * 128 + t];
        s_mean[t] = v * (1.0f / (float)NN);
    }
    __syncthreads();
    {   // query[d] = mean.Wf[:,d] + sc.Ws[:,d], 8-way split
        const int d = t & 127, p = t >> 7;
        float a = 0.f;
        for (int i = 16 * p; i < 16 * p + 16; ++i)
            a = fmaf(s_mean[i], Wf[i * DD + d], a);
        const float* scb = stepc + (size_t)b * CTXN;
        const int c0 = 16 * p, c1 = (p == 7) ? CTXN : 16 * p + 16;
        for (int c = c0; c < c1; ++c)
            a = fmaf(scb[c], Ws[c * DD + d], a);
        S[p * 128 + d] = a;
    }
    __syncthreads();
    if (t < 128) {
        float v = 0.f;
        #pragma unroll
        for (int p = 0; p < 8; ++p) v += S[p * 128 + t];
        s_q[t] = v;
    }
    __syncthreads();
    {   // qproj one-shot: thread (i = t&127, h = t>>7)
        const int i = t & 127, h = t >> 7;
        float a = 0.f;
        #pragma unroll
        for (int j = 0; j < 16; ++j)
            a = fmaf(Wn[i * 384 + h * 16 + j], s_q[h * 16 + j], a);
        qpt[(size_t)b * 1024 + h * 128 + i] = a * 0.25f;  // 1/sqrt(16)
    }
    // ---- compaction: unmasked row indices, ascending ----
    {
        const unsigned char* mk8 = (const unsigned char*)maskp + (size_t)b * NN;
        const int* mk32 = (const int*)maskp + (size_t)b * NN;
        int um = 0;
        if (t < NN) um = s_misint ? (mk32[t] == 0) : (mk8[t] == 0);
        const unsigned long long bal = __ballot(um);
        if (lane == 0) s_bal[w] = bal;
        __syncthreads();
        if (t == 0) {
            int o = 0;
            #pragma unroll
            for (int w2 = 0; w2 < 16; ++w2) {
                s_woff[w2] = o;
                o += (int)__popcll(s_bal[w2]);
            }
            cntv[b] = o;
        }
        __syncthreads();
        if (um) {
            const int pos = s_woff[w] +
                (int)__popcll(bal & ((lane == 0) ? 0ULL : (~0ULL >> (64 - lane))));
            idxv[(size_t)b * 1024 + pos] = t;
        }
    }
}

// ---------------- KB: slim streaming + headsp fold epilogue ----------------
// lane = (rg, cl): rg in [0,4) = head PAIR (heads 2rg, 2rg+1); cl = col octet.
// Wave w does compact position it*8 + w. <=64 VGPR; 4 blk/CU (LDS 38.6 KB).
__global__ __launch_bounds__(512, 4)
void kB_stream(const float* __restrict__ emb, const float* __restrict__ qpt,
               const float* __restrict__ Wn,
               const int* __restrict__ idxv, const int* __restrict__ cntv,
               float* __restrict__ headsp, float* __restrict__ stats) {
    const int b = blockIdx.x >> 3, s = blockIdx.x & 7;
    const int t = threadIdx.x, w = t >> 6, lane = t & 63;
    const int rg = lane >> 4, cl = lane & 15;
    const int cnt = cntv[b];
    const int lo = (s * cnt) >> 3;          // balanced: slice s gets ~cnt/8 rows
    const int hi = ((s + 1) * cnt) >> 3;
    const int nrows = hi - lo;              // <= 125
    const float* eb = emb + (size_t)b * (NN * DD);
    __shared__ __align__(16) float s_qpT[1024];         // 4 KB
    __shared__ __align__(16) float s_part[8 * 8 * 132]; // 33.8 KB; reused in epilogue
    __shared__ float s_sumw[64];
    __shared__ int s_idx[128];
    for (int i = t; i < 1024; i += 512) s_qpT[i] = qpt[(size_t)b * 1024 + i];
    if (t < 128) s_idx[t] = (t < nrows) ? idxv[(size_t)b * 1024 + lo + t] : 0;
    __syncthreads();
    const int h0 = 2 * rg, h1 = 2 * rg + 1;
    const float4 qa0 = *(const float4*)&s_qpT[h0 * 128 + cl * 8];
    const float4 qa1 = *(const float4*)&s_qpT[h0 * 128 + cl * 8 + 4];
    const float4 qb0 = *(const float4*)&s_qpT[h1 * 128 + cl * 8];
    const float4 qb1 = *(const float4*)&s_qpT[h1 * 128 + cl * 8 + 4];
    float4 a0A = make_float4(0.f,0.f,0.f,0.f), a0B = a0A;   // head h0, cols lo/hi
    float4 a1A = a0A, a1B = a0A;                            // head h1
    float ps0 = 0.f, ps1 = 0.f;
    // ---- branchless main iterations (all 8 wave-positions valid) ----
    const int mainIt = nrows >> 3;
    for (int it = 0; it < mainIt; ++it) {
        const int rp = it * 8 + w;
        const int n = s_idx[rp];
        const float4 e0 = *(const float4*)(eb + (size_t)n * DD + cl * 8);
        const float4 e1 = *(const float4*)(eb + (size_t)n * DD + cl * 8 + 4);
        float c0 = e0.x * qa0.x;
        c0 = fmaf(e0.y, qa0.y, c0); c0 = fmaf(e0.z, qa0.z, c0); c0 = fmaf(e0.w, qa0.w, c0);
        c0 = fmaf(e1.x, qa1.x, c0); c0 = fmaf(e1.y, qa1.y, c0);
        c0 = fmaf(e1.z, qa1.z, c0); c0 = fmaf(e1.w, qa1.w, c0);
        float c1 = e0.x * qb0.x;
        c1 = fmaf(e0.y, qb0.y, c1); c1 = fmaf(e0.z, qb0.z, c1); c1 = fmaf(e0.w, qb0.w, c1);
        c1 = fmaf(e1.x, qb1.x, c1); c1 = fmaf(e1.y, qb1.y, c1);
        c1 = fmaf(e1.z, qb1.z, c1); c1 = fmaf(e1.w, qb1.w, c1);
        c0 += __shfl_xor(c0, 1, 16); c1 += __shfl_xor(c1, 1, 16);
        c0 += __shfl_xor(c0, 2, 16); c1 += __shfl_xor(c1, 2, 16);
        c0 += __shfl_xor(c0, 4, 16); c1 += __shfl_xor(c1, 4, 16);
        c0 += __shfl_xor(c0, 8, 16); c1 += __shfl_xor(c1, 8, 16);
        const float p0 = __expf(fminf(c0, 80.f));
        const float p1 = __expf(fminf(c1, 80.f));
        ps0 += p0; ps1 += p1;
        a0A.x = fmaf(p0, e0.x, a0A.x); a0A.y = fmaf(p0, e0.y, a0A.y);
        a0A.z = fmaf(p0, e0.z, a0A.z); a0A.w = fmaf(p0, e0.w, a0A.w);
        a0B.x = fmaf(p0, e1.x, a0B.x); a0B.y = fmaf(p0, e1.y, a0B.y);
        a0B.z = fmaf(p0, e1.z, a0B.z); a0B.w = fmaf(p0, e1.w, a0B.w);
        a1A.x = fmaf(p1, e0.x, a1A.x); a1A.y = fmaf(p1, e0.y, a1A.y);
        a1A.z = fmaf(p1, e0.z, a1A.z); a1A.w = fmaf(p1, e0.w, a1A.w);
        a1B.x = fmaf(p1, e1.x, a1B.x); a1B.y = fmaf(p1, e1.y, a1B.y);
        a1B.z = fmaf(p1, e1.z, a1B.z); a1B.w = fmaf(p1, e1.w, a1B.w);
    }
    // ---- guarded tail (at most one iteration) ----
    if (mainIt * 8 < nrows) {
        const int rp = mainIt * 8 + w;
        const bool valid = (rp < nrows);
        const int n = s_idx[rp & 127];
        float4 e0 = make_float4(0.f,0.f,0.f,0.f), e1 = e0;
        if (valid) {
            e0 = *(const float4*)(eb + (size_t)n * DD + cl * 8);
            e1 = *(const float4*)(eb + (size_t)n * DD + cl * 8 + 4);
        }
        float c0 = e0.x * qa0.x;
        c0 = fmaf(e0.y, qa0.y, c0); c0 = fmaf(e0.z, qa0.z, c0); c0 = fmaf(e0.w, qa0.w, c0);
        c0 = fmaf(e1.x, qa1.x, c0); c0 = fmaf(e1.y, qa1.y, c0);
        c0 = fmaf(e1.z, qa1.z, c0); c0 = fmaf(e1.w, qa1.w, c0);
        float c1 = e0.x * qb0.x;
        c1 = fmaf(e0.y, qb0.y, c1); c1 = fmaf(e0.z, qb0.z, c1); c1 = fmaf(e0.w, qb0.w, c1);
        c1 = fmaf(e1.x, qb1.x, c1); c1 = fmaf(e1.y, qb1.y, c1);
        c1 = fmaf(e1.z, qb1.z, c1); c1 = fmaf(e1.w, qb1.w, c1);
        c0 += __shfl_xor(c0, 1, 16); c1 += __shfl_xor(c1, 1, 16);
        c0 += __shfl_xor(c0, 2, 16); c1 += __shfl_xor(c1, 2, 16);
        c0 += __shfl_xor(c0, 4, 16); c1 += __shfl_xor(c1, 4, 16);
        c0 += __shfl_xor(c0, 8, 16); c1 += __shfl_xor(c1, 8, 16);
        const float p0 = valid ? __expf(fminf(c0, 80.f)) : 0.f;
        const float p1 = valid ? __expf(fminf(c1, 80.f)) : 0.f;
        ps0 += p0; ps1 += p1;
        a0A.x = fmaf(p0, e0.x, a0A.x); a0A.y = fmaf(p0, e0.y, a0A.y);
        a0A.z = fmaf(p0, e0.z, a0A.z); a0A.w = fmaf(p0, e0.w, a0A.w);
        a0B.x = fmaf(p0, e1.x, a0B.x); a0B.y = fmaf(p0, e1.y, a0B.y);
        a0B.z = fmaf(p0, e1.z, a0B.z); a0B.w = fmaf(p0, e1.w, a0B.w);
        a1A.x = fmaf(p1, e0.x, a1A.x); a1A.y = fmaf(p1, e0.y, a1A.y);
        a1A.z = fmaf(p1, e0.z, a1A.z); a1A.w = fmaf(p1, e0.w, a1A.w);
        a1B.x = fmaf(p1, e1.x, a1B.x); a1B.y = fmaf(p1, e1.y, a1B.y);
        a1B.z = fmaf(p1, e1.z, a1B.z); a1B.w = fmaf(p1, e1.w, a1B.w);
    }
    // direct per-lane write: lane covers (h0,h1) x cols cl*8..+8
    *(float4*)&s_part[(w * 8 + h0) * 132 + cl * 8]     = a0A;
    *(float4*)&s_part[(w * 8 + h0) * 132 + cl * 8 + 4] = a0B;
    *(float4*)&s_part[(w * 8 + h1) * 132 + cl * 8]     = a1A;
    *(float4*)&s_part[(w * 8 + h1) * 132 + cl * 8 + 4] = a1B;
    if (cl == 0) { s_sumw[w * 8 + h0] = ps0; s_sumw[w * 8 + h1] = ps1; }
    __syncthreads();
    // ---- reduce wave partials, stash wemb_s into s_part[0..1024) ----
    float vres0, vres1;
    {
        const int i0 = t, i1 = t + 512;
        const int hA = i0 >> 7, cA = i0 & 127;
        const int hB = i1 >> 7, cB = i1 & 127;
        float v0 = 0.f, v1 = 0.f;
        #pragma unroll
        for (int w2 = 0; w2 < 8; ++w2) {
            v0 += s_part[(w2 * 8 + hA) * 132 + cA];
            v1 += s_part[(w2 * 8 + hB) * 132 + cB];
        }
        vres0 = v0; vres1 = v1;
    }
    __syncthreads();
    s_part[t]       = vres0;
    s_part[t + 512] = vres1;
    __syncthreads();
    // ---- headsp_s[j] = sum_i Wv[i,j] * wemb_s[j>>4][i], 4-way i-split ----
    {
        const int j = t & 127, p = t >> 7;
        const int h = j >> 4;
        float a = 0.f;
        for (int i = 32 * p; i < 32 * p + 32; ++i)
            a = fmaf(Wn[i * 384 + 128 + j], s_part[h * 128 + i], a);
        s_part[1024 + p * 128 + j] = a;
    }
    __syncthreads();
    if (t < 128)
        headsp[(size_t)b * 1024 + s * 128 + t] =
            s_part[1024 + t] + s_part[1024 + 128 + t] +
            s_part[1024 + 256 + t] + s_part[1024 + 384 + t];
    if (t < 8) {
        float v = 0.f;
        #pragma unroll
        for (int w2 = 0; w2 < 8; ++w2) v += s_sumw[w2 * 8 + t];
        stats[(size_t)b * 64 + s * 8 + t] = v;
    }
}

// ---------------- K4': heads merge -> glimpse -> g2 -> logits -> log_softmax ----------------
__global__ __launch_bounds__(1024, 4)
void k4_fused(const float* __restrict__ emb, const float* __restrict__ headsp,
              const float* __restrict__ stats,
              const float* __restrict__ Wn, const float* __restrict__ Wo,
              const int* __restrict__ idxv, const int* __restrict__ cntv,
              float* __restrict__ out) {
    const int b = blockIdx.x, t = threadIdx.x;
    const int w = t >> 6, lane = t & 63;
    const int rg = lane >> 4, cl = lane & 15;
    const float* eb = emb + (size_t)b * (NN * DD);
    __shared__ float s_dinv[8];
    __shared__ __align__(16) float s_red[1024];
    __shared__ float s_h[128], s_gl[128], s_g2[128];
    __shared__ float s_logits[1000];
    __shared__ int s_idxf[1024];
    __shared__ float s_r2[32];
    __shared__ float s_lse;
    const int cnt = cntv[b];
    if (t < NN) s_logits[t] = NEG_BIG;           // masked rows stay NEG_BIG
    s_idxf[t] = (t < cnt) ? idxv[(size_t)b * 1024 + t] : 0;
    // ---- dinv[h] = 1 / sum_s psum_s[h] (shared shift C=0) ----
    if (t < 8) {
        float den = 0.f;
        #pragma unroll
        for (int ss = 0; ss < 8; ++ss) den += stats[(size_t)b * 64 + ss * 8 + t];
        s_dinv[t] = 1.0f / den;
    }
    __syncthreads();
    // ---- heads[j] = dinv[j>>4] * sum_s headsp_s[j] (linearity fold) ----
    if (t < 128) {
        float v = 0.f;
        #pragma unroll
        for (int ss = 0; ss < 8; ++ss) v += headsp[(size_t)b * 1024 + ss * 128 + t];
        s_h[t] = v * s_dinv[t >> 4];
    }
    __syncthreads();
    {   // glimpse[d] = sum_j heads[j] Wo[j,d], 8-way j-split
        const int d = t & 127, p = t >> 7;
        float a = 0.f;
        for (int j = 16 * p; j < 16 * p + 16; ++j)
            a = fmaf(s_h[j], Wo[j * DD + d], a);
        s_red[p * 128 + d] = a;
    }
    __syncthreads();
    if (t < 128) {
        float v = 0.f;
        #pragma unroll
        for (int p = 0; p < 8; ++p) v += s_red[p * 128 + t];
        s_gl[t] = v;
    }
    __syncthreads();
    {   // g2[i] = (1/sqrt(128)) sum_d Wl[i,d] glimpse[d]
        const int i = t & 127, p = t >> 7;
        float a = 0.f;
        for (int d = 16 * p; d < 16 * p + 16; ++d)
            a = fmaf(Wn[i * 384 + 256 + d], s_gl[d], a);
        s_red[p * 128 + i] = a;
    }
    __syncthreads();
    if (t < 128) {
        float v = 0.f;
        #pragma unroll
        for (int p = 0; p < 8; ++p) v += s_red[p * 128 + t];
        s_g2[t] = v * 0.08838834764831845f;
    }
    __syncthreads();
    // ---- logits over compacted rows: branchless main + guarded tail ----
    {
        const float4 ga = *(const float4*)&s_g2[cl * 8];
        const float4 gb = *(const float4*)&s_g2[cl * 8 + 4];
        const int mainL = cnt >> 6;             // 64 positions per iteration
        for (int it = 0; it < mainL; ++it) {
            const int pos = it * 64 + w * 4 + rg;   // pos < cnt guaranteed
            const int n = s_idxf[pos];
            const float4 e0 = *(const float4*)(eb + (size_t)n * DD + cl * 8);
            const float4 e1 = *(const float4*)(eb + (size_t)n * DD + cl * 8 + 4);
            float a = e0.x * ga.x;
            a = fmaf(e0.y, ga.y, a);
            a = fmaf(e0.z, ga.z, a);
            a = fmaf(e0.w, ga.w, a);
            a = fmaf(e1.x, gb.x, a);
            a = fmaf(e1.y, gb.y, a);
            a = fmaf(e1.z, gb.z, a);
            a = fmaf(e1.w, gb.w, a);
            a += __shfl_xor(a, 1, 16);
            a += __shfl_xor(a, 2, 16);
            a += __shfl_xor(a, 4, 16);
            a += __shfl_xor(a, 8, 16);
            if (cl == 0)
                s_logits[n] = 10.0f * fast_tanh(a);
        }
        if (mainL * 64 < cnt) {                 // guarded tail
            const int pos = mainL * 64 + w * 4 + rg;
            const bool valid = (pos < cnt);
            const int n = s_idxf[pos & 1023];
            float a = 0.f;
            if (valid) {
                const float4 e0 = *(const float4*)(eb + (size_t)n * DD + cl * 8);
                const float4 e1 = *(const float4*)(eb + (size_t)n * DD + cl * 8 + 4);
                a = e0.x * ga.x;
                a = fmaf(e0.y, ga.y, a);
                a = fmaf(e0.z, ga.z, a);
                a = fmaf(e0.w, ga.w, a);
                a = fmaf(e1.x, gb.x, a);
                a = fmaf(e1.y, gb.y, a);
                a = fmaf(e1.z, gb.z, a);
                a = fmaf(e1.w, gb.w, a);
            }
            a += __shfl_xor(a, 1, 16);
            a += __shfl_xor(a, 2, 16);
            a += __shfl_xor(a, 4, 16);
            a += __shfl_xor(a, 8, 16);
            if (cl == 0 && valid)
                s_logits[n] = 10.0f * fast_tanh(a);
        }
    }
    __syncthreads();
    // ---- max-free log_softmax: |logits| <= 10 -> exp in [4.5e-5, 2.2e4];
    //      masked rows: __expf(NEG_BIG) = 0 exactly.
    {
        float sum = (t < NN) ? __expf(s_logits[t]) : 0.f;
        #pragma unroll
        for (int o = 32; o; o >>= 1) sum += __shfl_xor(sum, o, 64);
        if (lane == 0) s_r2[w] = sum;
        __syncthreads();
        if (t == 0) {
            float ss = 0.f;
            #pragma unroll
            for (int i = 0; i < 16; ++i) ss += s_r2[i];
            s_lse = logf(ss);
        }
        __syncthreads();
        if (t < NN) out[(size_t)b * NN + t] = s_logits[t] - s_lse;
    }
}

extern "C" void kernel_launch(void* const* d_in, const int* in_sizes, int n_in,
                              void* d_out, int out_size, void* d_ws, size_t ws_size,
                              hipStream_t stream) {
    const float* emb   = (const float*)d_in[0];
    const float* stepc = (const float*)d_in[1];
    const void*  mask  = (const void*)d_in[2];
    const float* Wn = (const float*)d_in[3];
    const float* Wf = (const float*)d_in[4];
    const float* Ws = (const float*)d_in[5];
    const float* Wo = (const float*)d_in[6];
    float* out = (float*)d_out;
    const int B = in_sizes[0] / (NN * DD);  // 256

    float* wsf = (float*)d_ws;
    const size_t n_qpt   = (size_t)B * 1024;
    const size_t n_hp    = (size_t)B * 1024;
    const size_t n_stats = (size_t)B * 64;
    const size_t n_idx   = (size_t)B * 1024;

    float* qpt    = wsf;
    float* headsp = qpt + n_qpt;
    float* stats  = headsp + n_hp;
    int*   idxv   = (int*)(stats + n_stats);
    int*   cntv   = idxv + n_idx;

    k1_fused <<<B,     1024, 0, stream>>>(emb, stepc, mask, Wn, Wf, Ws, qpt, idxv, cntv);
    kB_stream<<<B * 8, 512,  0, stream>>>(emb, qpt, Wn, idxv, cntv, headsp, stats);
    k4_fused <<<B,     1024, 0, stream>>>(emb, headsp, stats, Wn, Wo, idxv, cntv, out);
}